// Round 7
// baseline (197.933 us; speedup 1.0000x reference)
//
#include <hip/hip_runtime.h>
#include <hip/hip_bf16.h>

typedef __attribute__((ext_vector_type(8))) short short8;
typedef __attribute__((ext_vector_type(4))) float f32x4;
typedef __attribute__((ext_vector_type(4))) unsigned short u16x4;

#define MFMA16(a,b,c) __builtin_amdgcn_mfma_f32_16x16x32_bf16((a),(b),(c),0,0,0)

__device__ __forceinline__ ushort f2bf(float x) {
  union { float f; unsigned u; } v; v.f = x;
  unsigned u = v.u;
  u = (u + 0x7fffu + ((u >> 16) & 1u)) >> 16;
  return (ushort)u;
}

__device__ __forceinline__ float bf2f(ushort u) {
  union { unsigned u; float f; } v; v.u = ((unsigned)u) << 16;
  return v.f;
}

__device__ __forceinline__ short8 ld8(const ushort* p) {
  return *reinterpret_cast<const short8*>(p);
}

__device__ __forceinline__ f32x4 ldnt4(const float* p) {
  return __builtin_nontemporal_load(reinterpret_cast<const f32x4*>(p));
}

// ---- kernel 0: fp32 -> bf16 conversion (vectorized float4 -> ushort4) ----
__global__ void conv_kernel(const float* __restrict__ value,
                            const float* __restrict__ w_in,
                            const float* __restrict__ w_out,
                            ushort* __restrict__ vbf,
                            ushort* __restrict__ wbf,
                            ushort* __restrict__ owbf) {
  int i = blockIdx.x * 256 + threadIdx.x;   // float4 index
  const float* src; ushort* dst; int j;
  if (i < 524288)      { src = value; dst = vbf;  j = i; }
  else if (i < 573440) { src = w_in;  dst = wbf;  j = i - 524288; }
  else                 { src = w_out; dst = owbf; j = i - 573440; }
  float4 v = reinterpret_cast<const float4*>(src)[j];
  u16x4 o;
  o[0] = f2bf(v.x); o[1] = f2bf(v.y); o[2] = f2bf(v.z); o[3] = f2bf(v.w);
  reinterpret_cast<u16x4*>(dst)[j] = o;
}

// ---- kernel 1: qkv projection GEMM (8192x256)@(256x768)^T, scatter to head layouts ----
__global__ __launch_bounds__(256) void qkv_kernel(
    const ushort* __restrict__ vbf, const ushort* __restrict__ wbf,
    const float* __restrict__ bias,
    ushort* __restrict__ qh, ushort* __restrict__ kh, ushort* __restrict__ vv) {
  int tid = threadIdx.x;
  int wave = tid >> 6, lane = tid & 63;
  int lq = lane & 15, lg = lane >> 4;
  int r0 = blockIdx.x * 16;
  int c0 = (blockIdx.y * 4 + wave) * 16;
  f32x4 acc = {0.f, 0.f, 0.f, 0.f};
  const ushort* ap = vbf + (size_t)(r0 + lq) * 256 + lg * 8;
  const ushort* bp = wbf + (size_t)(c0 + lq) * 256 + lg * 8;
#pragma unroll
  for (int k0 = 0; k0 < 256; k0 += 32)
    acc = MFMA16(ld8(ap + k0), ld8(bp + k0), acc);
  int c = c0 + lq;
  float bv = bias[c];
#pragma unroll
  for (int r = 0; r < 4; ++r) {
    int row = r0 + lg * 4 + r;       // row = n*8 + b
    int n = row >> 3, b = row & 7;
    float v = acc[r] + bv;
    if (c < 256) {
      int h = c >> 5, d = c & 31;
      qh[((size_t)(b * 8 + h) * 1024 + n) * 32 + d] = f2bf(v * 0.17677669529663689f);
    } else if (c < 512) {
      int cc = c - 256, h = cc >> 5, d = cc & 31;
      kh[((size_t)(b * 8 + h) * 1024 + n) * 32 + d] = f2bf(v);
    } else {
      int cc = c - 512, h = cc >> 5, d = cc & 31;
      vv[((size_t)(b * 8 + h) * 1024 + n) * 32 + d] = f2bf(v);
    }
  }
}

// ---- kernel 1b: transpose vv[bh][m][d] -> vt[bh][d][m], coalesced both sides ----
__global__ __launch_bounds__(256) void vtrans_kernel(const ushort* __restrict__ vv,
                                                     ushort* __restrict__ vt) {
  __shared__ ushort t[32][73];
  int tid = threadIdx.x;
  int bh = blockIdx.y, m0 = blockIdx.x * 64;
  int mm = tid >> 2, d0 = (tid & 3) * 8;
  short8 v = ld8(vv + ((size_t)bh * 1024 + m0 + mm) * 32 + d0);
#pragma unroll
  for (int j = 0; j < 8; ++j) t[d0 + j][mm] = (ushort)v[j];
  __syncthreads();
  int d = tid >> 3, mg = (tid & 7) * 8;
  short8 o;
#pragma unroll
  for (int j = 0; j < 8; ++j) o[j] = (short)t[d][mg + j];
  *reinterpret_cast<short8*>(vt + ((size_t)bh * 32 + d) * 1024 + m0 + mg) = o;
}

// ---- kernel 2: fused attention, register-resident swapped-MFMA pipeline.
// 256 threads = 4 waves; wave w owns m-window [w*256, w*256+256), 8 u-steps of 32.
// QK^T computed as mfma(K_perm, Q) so lane (lq,lg) holds S[m=mu+lg*8+i][n=lq] for
// i=0..7; gating is lane-local (pos as 2x float4); gated bf16 w8 IS the PV A-frag.
// No LDS for weights; one barrier per head (double-buffered pvred/rowsumT).
__global__ __launch_bounds__(256, 2) void attn_kernel(
    const ushort* __restrict__ qh, const ushort* __restrict__ kh,
    const ushort* __restrict__ vt, const float* __restrict__ pos,
    ushort* __restrict__ ao, float* __restrict__ avg_out) {
  __shared__ float pvred[2][4][16][32];   // 16 KB
  __shared__ float rowsumT[2][16][4];     // 512 B

  int tid = threadIdx.x;
  int wave = tid >> 6, lane = tid & 63;
  int lq = lane & 15, lg = lane >> 4;
  int n0 = blockIdx.x * 16;
  int b = blockIdx.y;
  int wbase = wave * 256;
  int ra = ((lq >> 2) << 3) + (lq & 3);   // permuted K-row offset {0-3,8-11,16-19,24-27}

  float avg[8][8];
#pragma unroll
  for (int u = 0; u < 8; ++u)
#pragma unroll
    for (int i = 0; i < 8; ++i) avg[u][i] = 0.f;

  for (int h = 0; h < 8; ++h) {
    int bh = b * 8 + h;
    const ushort* kp = kh + (size_t)bh * 32768;
    const ushort* vp = vt + (size_t)bh * 32768;
    const float* ppr = pos + ((size_t)bh << 20) + (size_t)(n0 + lq) * 1024 + wbase;
    short8 qa = ld8(qh + ((size_t)bh * 1024 + n0 + lq) * 32 + lg * 8);

    f32x4 acc0 = {0.f, 0.f, 0.f, 0.f}, acc1 = {0.f, 0.f, 0.f, 0.f};
    float rs = 0.f;
    short8 wh[8];

#pragma unroll
    for (int u = 0; u < 8; ++u) {
      int mu = wbase + u * 32;
      short8 ka = ld8(kp + (size_t)(mu + ra) * 32 + lg * 8);
      short8 kb = ld8(kp + (size_t)(mu + ra + 4) * 32 + lg * 8);
      f32x4 p0 = ldnt4(ppr + u * 32 + lg * 8);
      f32x4 p1 = ldnt4(ppr + u * 32 + lg * 8 + 4);
      f32x4 z = {0.f, 0.f, 0.f, 0.f};
      f32x4 SA = MFMA16(ka, qa, z);   // SA[i] = S[mu+lg*8+i][n=lq]
      f32x4 SB = MFMA16(kb, qa, z);   // SB[i] = S[mu+lg*8+4+i][n=lq]
      short8 w8;
#pragma unroll
      for (int i = 0; i < 4; ++i) {
        float p = fminf(10.f, fmaxf(-10.f, p0[i]));
        float c = fminf(10.f, fmaxf(-10.f, SA[i]));
        float w = __expf(c - 10.f) * __builtin_amdgcn_rcpf(1.f + __expf(-p));
        rs += w;
        w8[i] = (short)f2bf(w);
      }
#pragma unroll
      for (int i = 0; i < 4; ++i) {
        float p = fminf(10.f, fmaxf(-10.f, p1[i]));
        float c = fminf(10.f, fmaxf(-10.f, SB[i]));
        float w = __expf(c - 10.f) * __builtin_amdgcn_rcpf(1.f + __expf(-p));
        rs += w;
        w8[4 + i] = (short)f2bf(w);
      }
      wh[u] = w8;
      // PV: A = w8 (rows n=lq, k-slice m), B = V^T rows d
      acc0 = MFMA16(w8, ld8(vp + (size_t)lq * 1024 + mu + lg * 8), acc0);
      acc1 = MFMA16(w8, ld8(vp + (size_t)(lq + 16) * 1024 + mu + lg * 8), acc1);
    }
    // wave-partial rowsum for row n=lq (reduce across the 4 lg groups)
    rs += __shfl_xor(rs, 16);
    rs += __shfl_xor(rs, 32);
    int buf = h & 1;
    if (lane < 16) rowsumT[buf][lq][wave] = rs;
#pragma unroll
    for (int j = 0; j < 4; ++j) {
      pvred[buf][wave][lg * 4 + j][lq] = acc0[j];        // O[n=lg*4+j][d=lq]
      pvred[buf][wave][lg * 4 + j][lq + 16] = acc1[j];
    }
    __syncthreads();                     // the only barrier per head
    // epilogue (overlaps next head's loads): normalize avg + combine PV
    {
      float invr = __builtin_amdgcn_rcpf(rowsumT[buf][lq][0] + rowsumT[buf][lq][1] +
                                         rowsumT[buf][lq][2] + rowsumT[buf][lq][3]);
#pragma unroll
      for (int u = 0; u < 8; ++u)
#pragma unroll
        for (int i = 0; i < 8; ++i)
          avg[u][i] += bf2f((ushort)wh[u][i]) * invr;
      int n = tid >> 4, d = tid & 15;
      float invn = __builtin_amdgcn_rcpf(rowsumT[buf][n][0] + rowsumT[buf][n][1] +
                                         rowsumT[buf][n][2] + rowsumT[buf][n][3]);
      float s0 = pvred[buf][0][n][d] + pvred[buf][1][n][d] +
                 pvred[buf][2][n][d] + pvred[buf][3][n][d];
      float s1 = pvred[buf][0][n][d + 16] + pvred[buf][1][n][d + 16] +
                 pvred[buf][2][n][d + 16] + pvred[buf][3][n][d + 16];
      size_t base = ((size_t)(n0 + n) * 8 + b) * 256 + h * 32;
      ao[base + d] = f2bf(s0 * invn);
      ao[base + d + 16] = f2bf(s1 * invn);
    }
  }
  // ---- averaged attention (mean over heads): row n0+lq, cols wbase+u*32+lg*8 ----
  float* op = avg_out + (size_t)b * 1048576 + (size_t)(n0 + lq) * 1024 + wbase;
#pragma unroll
  for (int u = 0; u < 8; ++u) {
    f32x4 v0 = {avg[u][0] * 0.125f, avg[u][1] * 0.125f, avg[u][2] * 0.125f, avg[u][3] * 0.125f};
    f32x4 v1 = {avg[u][4] * 0.125f, avg[u][5] * 0.125f, avg[u][6] * 0.125f, avg[u][7] * 0.125f};
    __builtin_nontemporal_store(v0, reinterpret_cast<f32x4*>(op + u * 32 + lg * 8));
    __builtin_nontemporal_store(v1, reinterpret_cast<f32x4*>(op + u * 32 + lg * 8 + 4));
  }
}

// ---- kernel 3: output projection (8192x256)@(256x256)^T + bias -> d_out (fp32) ----
__global__ __launch_bounds__(256) void oproj_kernel(
    const ushort* __restrict__ ao, const ushort* __restrict__ owbf,
    const float* __restrict__ ob, float* __restrict__ outp) {
  int tid = threadIdx.x;
  int wave = tid >> 6, lane = tid & 63;
  int lq = lane & 15, lg = lane >> 4;
  int r0 = blockIdx.x * 16;
  int c0 = (blockIdx.y * 4 + wave) * 16;
  f32x4 acc = {0.f, 0.f, 0.f, 0.f};
  const ushort* ap = ao + (size_t)(r0 + lq) * 256 + lg * 8;
  const ushort* bp = owbf + (size_t)(c0 + lq) * 256 + lg * 8;
#pragma unroll
  for (int k0 = 0; k0 < 256; k0 += 32)
    acc = MFMA16(ld8(ap + k0), ld8(bp + k0), acc);
  int c = c0 + lq;
  float bv = ob[c];
#pragma unroll
  for (int r = 0; r < 4; ++r) {
    int row = r0 + lg * 4 + r;
    outp[(size_t)row * 256 + c] = acc[r] + bv;
  }
}

extern "C" void kernel_launch(void* const* d_in, const int* in_sizes, int n_in,
                              void* d_out, int out_size, void* d_ws, size_t ws_size,
                              hipStream_t stream) {
  const float* value = (const float*)d_in[0];
  const float* pos   = (const float*)d_in[1];
  const float* w_in  = (const float*)d_in[2];
  const float* b_in  = (const float*)d_in[3];
  const float* w_out = (const float*)d_in[4];
  const float* b_out = (const float*)d_in[5];

  char* ws = (char*)d_ws;
  ushort* vbf  = (ushort*)(ws);                 // 8192x256 bf16 (4 MB); reused as vt after qkv
  ushort* wbf  = (ushort*)(ws + 4194304);       // 768x256 bf16
  ushort* owbf = (ushort*)(ws + 4587520);       // 256x256 bf16
  ushort* qh   = (ushort*)(ws + 4718592);       // 64x1024x32 bf16 (4 MB)
  ushort* kh   = (ushort*)(ws + 8912896);       // 64x1024x32 bf16 (4 MB)
  ushort* vv   = (ushort*)(ws + 13107200);      // 64x1024x32 bf16 (4 MB, row-major V)
  ushort* vt   = (ushort*)(ws);                 // 64x32x1024 bf16 (4 MB, overlays dead vbf)
  ushort* ao   = (ushort*)(ws + 17301504);      // 8192x256 bf16 (4 MB)

  float* outp = (float*)d_out;                  // (N,B,E) fp32
  float* avgp = outp + 2097152;                 // (B,N,N) fp32

  conv_kernel<<<2304, 256, 0, stream>>>(value, w_in, w_out, vbf, wbf, owbf);
  qkv_kernel<<<dim3(512, 12), 256, 0, stream>>>(vbf, wbf, b_in, qh, kh, vv);
  vtrans_kernel<<<dim3(16, 64), 256, 0, stream>>>(vv, vt);
  attn_kernel<<<dim3(64, 8), 256, 0, stream>>>(qh, kh, vt, pos, ao, avgp);
  oproj_kernel<<<dim3(512, 4), 256, 0, stream>>>(ao, owbf, b_out, outp);
}

// Round 8
// 187.244 us; speedup vs baseline: 1.0571x; 1.0571x over previous
//
#include <hip/hip_runtime.h>
#include <hip/hip_bf16.h>

typedef __attribute__((ext_vector_type(8))) short short8;
typedef __attribute__((ext_vector_type(4))) float f32x4;
typedef __attribute__((ext_vector_type(4))) unsigned short u16x4;

#define MFMA16(a,b,c) __builtin_amdgcn_mfma_f32_16x16x32_bf16((a),(b),(c),0,0,0)

__device__ __forceinline__ ushort f2bf(float x) {
  union { float f; unsigned u; } v; v.f = x;
  unsigned u = v.u;
  u = (u + 0x7fffu + ((u >> 16) & 1u)) >> 16;
  return (ushort)u;
}

__device__ __forceinline__ float bf2f(ushort u) {
  union { unsigned u; float f; } v; v.u = ((unsigned)u) << 16;
  return v.f;
}

__device__ __forceinline__ short8 ld8(const ushort* p) {
  return *reinterpret_cast<const short8*>(p);
}

__device__ __forceinline__ f32x4 ld4(const float* p) {
  return *reinterpret_cast<const f32x4*>(p);
}

// ---- kernel 0: fp32 -> bf16 conversion (vectorized float4 -> ushort4) ----
__global__ void conv_kernel(const float* __restrict__ value,
                            const float* __restrict__ w_in,
                            const float* __restrict__ w_out,
                            ushort* __restrict__ vbf,
                            ushort* __restrict__ wbf,
                            ushort* __restrict__ owbf) {
  int i = blockIdx.x * 256 + threadIdx.x;   // float4 index
  const float* src; ushort* dst; int j;
  if (i < 524288)      { src = value; dst = vbf;  j = i; }
  else if (i < 573440) { src = w_in;  dst = wbf;  j = i - 524288; }
  else                 { src = w_out; dst = owbf; j = i - 573440; }
  float4 v = reinterpret_cast<const float4*>(src)[j];
  u16x4 o;
  o[0] = f2bf(v.x); o[1] = f2bf(v.y); o[2] = f2bf(v.z); o[3] = f2bf(v.w);
  reinterpret_cast<u16x4*>(dst)[j] = o;
}

// ---- kernel 1: qkv projection GEMM (8192x256)@(256x768)^T, scatter to head layouts ----
__global__ __launch_bounds__(256) void qkv_kernel(
    const ushort* __restrict__ vbf, const ushort* __restrict__ wbf,
    const float* __restrict__ bias,
    ushort* __restrict__ qh, ushort* __restrict__ kh, ushort* __restrict__ vv) {
  int tid = threadIdx.x;
  int wave = tid >> 6, lane = tid & 63;
  int lq = lane & 15, lg = lane >> 4;
  int r0 = blockIdx.x * 16;
  int c0 = (blockIdx.y * 4 + wave) * 16;
  f32x4 acc = {0.f, 0.f, 0.f, 0.f};
  const ushort* ap = vbf + (size_t)(r0 + lq) * 256 + lg * 8;
  const ushort* bp = wbf + (size_t)(c0 + lq) * 256 + lg * 8;
#pragma unroll
  for (int k0 = 0; k0 < 256; k0 += 32)
    acc = MFMA16(ld8(ap + k0), ld8(bp + k0), acc);
  int c = c0 + lq;
  float bv = bias[c];
#pragma unroll
  for (int r = 0; r < 4; ++r) {
    int row = r0 + lg * 4 + r;       // row = n*8 + b
    int n = row >> 3, b = row & 7;
    float v = acc[r] + bv;
    if (c < 256) {
      int h = c >> 5, d = c & 31;
      qh[((size_t)(b * 8 + h) * 1024 + n) * 32 + d] = f2bf(v * 0.17677669529663689f);
    } else if (c < 512) {
      int cc = c - 256, h = cc >> 5, d = cc & 31;
      kh[((size_t)(b * 8 + h) * 1024 + n) * 32 + d] = f2bf(v);
    } else {
      int cc = c - 512, h = cc >> 5, d = cc & 31;
      vv[((size_t)(b * 8 + h) * 1024 + n) * 32 + d] = f2bf(v);
    }
  }
}

// ---- kernel 1b: transpose vv[bh][m][d] -> vt[bh][d][m], coalesced both sides ----
__global__ __launch_bounds__(256) void vtrans_kernel(const ushort* __restrict__ vv,
                                                     ushort* __restrict__ vt) {
  __shared__ ushort t[32][73];
  int tid = threadIdx.x;
  int bh = blockIdx.y, m0 = blockIdx.x * 64;
  int mm = tid >> 2, d0 = (tid & 3) * 8;
  short8 v = ld8(vv + ((size_t)bh * 1024 + m0 + mm) * 32 + d0);
#pragma unroll
  for (int j = 0; j < 8; ++j) t[d0 + j][mm] = (ushort)v[j];
  __syncthreads();
  int d = tid >> 3, mg = (tid & 7) * 8;
  short8 o;
#pragma unroll
  for (int j = 0; j < 8; ++j) o[j] = (short)t[d][mg + j];
  *reinterpret_cast<short8*>(vt + ((size_t)bh * 32 + d) * 1024 + m0 + mg) = o;
}

// ---- kernel 2: fused attention, register-resident swapped-MFMA pipeline with
// DEPTH-2 pos prefetch ring. 256 threads = 4 waves; wave w owns m-window
// [w*256, w*256+256), 8 u-steps of 32 per head; global step g = h*8+u; at step g
// we issue the pos loads for step g+2 (cross-head continuation, no bubble).
__global__ __launch_bounds__(256, 2) void attn_kernel(
    const ushort* __restrict__ qh, const ushort* __restrict__ kh,
    const ushort* __restrict__ vt, const float* __restrict__ pos,
    ushort* __restrict__ ao, float* __restrict__ avg_out) {
  __shared__ float pvred[2][4][16][32];   // 16 KB
  __shared__ float rowsumT[2][16][4];     // 512 B

  int tid = threadIdx.x;
  int wave = tid >> 6, lane = tid & 63;
  int lq = lane & 15, lg = lane >> 4;
  int n0 = blockIdx.x * 16;
  int b = blockIdx.y;
  int wbase = wave * 256;
  int ra = ((lq >> 2) << 3) + (lq & 3);   // permuted K-row offset {0-3,8-11,16-19,24-27}

  float avg[8][8];
#pragma unroll
  for (int u = 0; u < 8; ++u)
#pragma unroll
    for (int i = 0; i < 8; ++i) avg[u][i] = 0.f;

  // per-lane pos base: row n0+lq, cols wbase + g-dependent offset
  const float* pbase = pos + ((size_t)(b * 8) << 20) + (size_t)(n0 + lq) * 1024 + wbase + lg * 8;

  // depth-2 prefetch ring: slot s holds pos for step g with (g&1)==s
  f32x4 pfa[2], pfb[2];
  pfa[0] = ld4(pbase);       pfb[0] = ld4(pbase + 4);        // g=0
  pfa[1] = ld4(pbase + 32);  pfb[1] = ld4(pbase + 36);       // g=1

  for (int h = 0; h < 8; ++h) {
    int bh = b * 8 + h;
    const ushort* kp = kh + (size_t)bh * 32768;
    const ushort* vp = vt + (size_t)bh * 32768;
    short8 qa = ld8(qh + ((size_t)bh * 1024 + n0 + lq) * 32 + lg * 8);

    f32x4 acc0 = {0.f, 0.f, 0.f, 0.f}, acc1 = {0.f, 0.f, 0.f, 0.f};
    float rs = 0.f;
    short8 wh[8];

#pragma unroll
    for (int u = 0; u < 8; ++u) {
      int mu = wbase + u * 32;
      // take copies of the ring slot, then the slot is free for reissue
      f32x4 p0 = pfa[u & 1];
      f32x4 p1 = pfb[u & 1];
      // issue this step's K loads
      short8 ka = ld8(kp + (size_t)(mu + ra) * 32 + lg * 8);
      short8 kb = ld8(kp + (size_t)(mu + ra + 4) * 32 + lg * 8);
      // issue pos prefetch for step g+2 into the freed slot (depth-2)
      {
        int g = h * 8 + u + 2;
        if (g < 64) {
          const float* np = pbase + ((size_t)(g >> 3) << 20) + (g & 7) * 32;
          pfa[u & 1] = ld4(np);
          pfb[u & 1] = ld4(np + 4);
        }
      }
      // issue this step's V loads
      short8 va = ld8(vp + (size_t)lq * 1024 + mu + lg * 8);
      short8 vb = ld8(vp + (size_t)(lq + 16) * 1024 + mu + lg * 8);
      // QK^T (swapped): SA[i] = S[mu+lg*8+i][n=lq], SB shifted by 4
      f32x4 z = {0.f, 0.f, 0.f, 0.f};
      f32x4 SA = MFMA16(ka, qa, z);
      f32x4 SB = MFMA16(kb, qa, z);
      short8 w8;
#pragma unroll
      for (int i = 0; i < 4; ++i) {
        float p = fminf(10.f, fmaxf(-10.f, p0[i]));
        float c = fminf(10.f, fmaxf(-10.f, SA[i]));
        float w = __expf(c - 10.f) * __builtin_amdgcn_rcpf(1.f + __expf(-p));
        rs += w;
        w8[i] = (short)f2bf(w);
      }
#pragma unroll
      for (int i = 0; i < 4; ++i) {
        float p = fminf(10.f, fmaxf(-10.f, p1[i]));
        float c = fminf(10.f, fmaxf(-10.f, SB[i]));
        float w = __expf(c - 10.f) * __builtin_amdgcn_rcpf(1.f + __expf(-p));
        rs += w;
        w8[4 + i] = (short)f2bf(w);
      }
      wh[u] = w8;
      // PV: A = w8 (rows n=lq, k-slice m), B = V^T rows d
      acc0 = MFMA16(w8, va, acc0);
      acc1 = MFMA16(w8, vb, acc1);
    }
    // wave-partial rowsum for row n=lq (reduce across the 4 lg groups)
    rs += __shfl_xor(rs, 16);
    rs += __shfl_xor(rs, 32);
    int buf = h & 1;
    if (lane < 16) rowsumT[buf][lq][wave] = rs;
#pragma unroll
    for (int j = 0; j < 4; ++j) {
      pvred[buf][wave][lg * 4 + j][lq] = acc0[j];        // O[n=lg*4+j][d=lq]
      pvred[buf][wave][lg * 4 + j][lq + 16] = acc1[j];
    }
    __syncthreads();                     // the only barrier per head
    // epilogue (pos prefetches for next head already in flight): normalize
    {
      float invr = __builtin_amdgcn_rcpf(rowsumT[buf][lq][0] + rowsumT[buf][lq][1] +
                                         rowsumT[buf][lq][2] + rowsumT[buf][lq][3]);
#pragma unroll
      for (int u = 0; u < 8; ++u)
#pragma unroll
        for (int i = 0; i < 8; ++i)
          avg[u][i] += bf2f((ushort)wh[u][i]) * invr;
      int n = tid >> 4, d = tid & 15;
      float invn = __builtin_amdgcn_rcpf(rowsumT[buf][n][0] + rowsumT[buf][n][1] +
                                         rowsumT[buf][n][2] + rowsumT[buf][n][3]);
      float s0 = pvred[buf][0][n][d] + pvred[buf][1][n][d] +
                 pvred[buf][2][n][d] + pvred[buf][3][n][d];
      float s1 = pvred[buf][0][n][d + 16] + pvred[buf][1][n][d + 16] +
                 pvred[buf][2][n][d + 16] + pvred[buf][3][n][d + 16];
      size_t base = ((size_t)(n0 + n) * 8 + b) * 256 + h * 32;
      ao[base + d] = f2bf(s0 * invn);
      ao[base + d + 16] = f2bf(s1 * invn);
    }
  }
  // ---- averaged attention (mean over heads): row n0+lq, cols wbase+u*32+lg*8 ----
  float* op = avg_out + (size_t)b * 1048576 + (size_t)(n0 + lq) * 1024 + wbase;
#pragma unroll
  for (int u = 0; u < 8; ++u) {
    f32x4 v0 = {avg[u][0] * 0.125f, avg[u][1] * 0.125f, avg[u][2] * 0.125f, avg[u][3] * 0.125f};
    f32x4 v1 = {avg[u][4] * 0.125f, avg[u][5] * 0.125f, avg[u][6] * 0.125f, avg[u][7] * 0.125f};
    __builtin_nontemporal_store(v0, reinterpret_cast<f32x4*>(op + u * 32 + lg * 8));
    __builtin_nontemporal_store(v1, reinterpret_cast<f32x4*>(op + u * 32 + lg * 8 + 4));
  }
}

// ---- kernel 3: output projection (8192x256)@(256x256)^T + bias -> d_out (fp32) ----
__global__ __launch_bounds__(256) void oproj_kernel(
    const ushort* __restrict__ ao, const ushort* __restrict__ owbf,
    const float* __restrict__ ob, float* __restrict__ outp) {
  int tid = threadIdx.x;
  int wave = tid >> 6, lane = tid & 63;
  int lq = lane & 15, lg = lane >> 4;
  int r0 = blockIdx.x * 16;
  int c0 = (blockIdx.y * 4 + wave) * 16;
  f32x4 acc = {0.f, 0.f, 0.f, 0.f};
  const ushort* ap = ao + (size_t)(r0 + lq) * 256 + lg * 8;
  const ushort* bp = owbf + (size_t)(c0 + lq) * 256 + lg * 8;
#pragma unroll
  for (int k0 = 0; k0 < 256; k0 += 32)
    acc = MFMA16(ld8(ap + k0), ld8(bp + k0), acc);
  int c = c0 + lq;
  float bv = ob[c];
#pragma unroll
  for (int r = 0; r < 4; ++r) {
    int row = r0 + lg * 4 + r;
    outp[(size_t)row * 256 + c] = acc[r] + bv;
  }
}

extern "C" void kernel_launch(void* const* d_in, const int* in_sizes, int n_in,
                              void* d_out, int out_size, void* d_ws, size_t ws_size,
                              hipStream_t stream) {
  const float* value = (const float*)d_in[0];
  const float* pos   = (const float*)d_in[1];
  const float* w_in  = (const float*)d_in[2];
  const float* b_in  = (const float*)d_in[3];
  const float* w_out = (const float*)d_in[4];
  const float* b_out = (const float*)d_in[5];

  char* ws = (char*)d_ws;
  ushort* vbf  = (ushort*)(ws);                 // 8192x256 bf16 (4 MB); reused as vt after qkv
  ushort* wbf  = (ushort*)(ws + 4194304);       // 768x256 bf16
  ushort* owbf = (ushort*)(ws + 4587520);       // 256x256 bf16
  ushort* qh   = (ushort*)(ws + 4718592);       // 64x1024x32 bf16 (4 MB)
  ushort* kh   = (ushort*)(ws + 8912896);       // 64x1024x32 bf16 (4 MB)
  ushort* vv   = (ushort*)(ws + 13107200);      // 64x1024x32 bf16 (4 MB, row-major V)
  ushort* vt   = (ushort*)(ws);                 // 64x32x1024 bf16 (4 MB, overlays dead vbf)
  ushort* ao   = (ushort*)(ws + 17301504);      // 8192x256 bf16 (4 MB)

  float* outp = (float*)d_out;                  // (N,B,E) fp32
  float* avgp = outp + 2097152;                 // (B,N,N) fp32

  conv_kernel<<<2304, 256, 0, stream>>>(value, w_in, w_out, vbf, wbf, owbf);
  qkv_kernel<<<dim3(512, 12), 256, 0, stream>>>(vbf, wbf, b_in, qh, kh, vv);
  vtrans_kernel<<<dim3(16, 64), 256, 0, stream>>>(vv, vt);
  attn_kernel<<<dim3(64, 8), 256, 0, stream>>>(qh, kh, vt, pos, ao, avgp);
  oproj_kernel<<<dim3(512, 4), 256, 0, stream>>>(ao, owbf, b_out, outp);
}